// Round 11
// baseline (149.975 us; speedup 1.0000x reference)
//
#include <hip/hip_runtime.h>
#include <hip/hip_bf16.h>

using f32x4 = __attribute__((ext_vector_type(4))) float;
using s16x8 = __attribute__((ext_vector_type(8))) short;

#define MFMA16x16x32(a, b, c) __builtin_amdgcn_mfma_f32_16x16x32_bf16((a), (b), (c), 0, 0, 0)

#define AS_G(p) ((const __attribute__((address_space(1))) void*)(p))
#define AS_L(p) ((__attribute__((address_space(3))) void*)(p))

// barrier with LDS-visibility only: does NOT drain vmcnt
#define BARRIER_LGKM() do { \
    asm volatile("s_waitcnt lgkmcnt(0)" ::: "memory"); \
    __builtin_amdgcn_s_barrier(); \
} while (0)

static __device__ __forceinline__ unsigned short f2bf(float f) {
    unsigned int u = __float_as_uint(f);
    u = (u + 0x7fffu + ((u >> 16) & 1u)) >> 16;
    return (unsigned short)u;
}
static __device__ __forceinline__ unsigned int cvt_pk_bf2(float lo, float hi) {
    unsigned int r;
    asm("v_cvt_pk_bf16_f32 %0, %1, %2" : "=v"(r) : "v"(lo), "v"(hi));
    return r;
}
// swizzled byte offsets — used IDENTICALLY on write and read sides
static __device__ __forceinline__ int swz128(int r, int c) { return (r * 128 + c) ^ ((r & 7) << 4); }
static __device__ __forceinline__ int swz256(int r, int c) { return (r * 256 + c) ^ ((r & 7) << 4); }

// ---- convert fp32 -> bf16 (vectorized) ----
__global__ void cvt_f32_bf16(const float* __restrict__ in, unsigned short* __restrict__ out, int n) {
    int i = (blockIdx.x * blockDim.x + threadIdx.x) * 4;
    int stride = gridDim.x * blockDim.x * 4;
    for (; i < n; i += stride) {
        float4 v = *(const float4*)(in + i);
        ushort4 o;
        o.x = f2bf(v.x); o.y = f2bf(v.y); o.z = f2bf(v.z); o.w = f2bf(v.w);
        *(ushort4*)(out + i) = o;
    }
}

// ---- LDS-tiled transpose+convert: wt[n][k] = bf16(w[k][n]) ----
__global__ __launch_bounds__(256)
void transpose_cvt_tiled(const float* __restrict__ w, unsigned short* __restrict__ wt,
                         int K, int N) {
    __shared__ float tile[32][33];
    const int tid = threadIdx.x;
    const int tx = tid & 31, ty = tid >> 5;
    const int n0 = blockIdx.x * 32, k0 = blockIdx.y * 32;
#pragma unroll
    for (int r = 0; r < 4; r++)
        tile[ty * 4 + r][tx] = w[(size_t)(k0 + ty * 4 + r) * N + n0 + tx];
    __syncthreads();
#pragma unroll
    for (int r = 0; r < 4; r++)
        wt[(size_t)(n0 + ty * 4 + r) * K + k0 + tx] = f2bf(tile[tx][ty * 4 + r]);
}

// ---- GEMM: C[M,N] = A[M,K] * Bt[N,K]^T + bias ----
// 128x128 tile, BK=64, 2-phase dbuf gload_lds staging, counted vmcnt.
template <bool OUT_BF16>
__global__ __launch_bounds__(256, 2)
void gemm_bt(const unsigned short* __restrict__ A, const unsigned short* __restrict__ Bt,
             const float* __restrict__ bias, void* __restrict__ Cout,
             unsigned short* __restrict__ Vt,
             int M, int N, int K, int ldc, int qcols, float qscale) {
    __shared__ char smem[65536];
    const int tid = threadIdx.x, wid = tid >> 6, lane = tid & 63;
    const int g = lane >> 4, lr = lane & 15;
    const int m0 = blockIdx.y * 128, n0 = blockIdx.x * 128;
    const int wm = wid >> 1, wn = wid & 1;

    f32x4 acc[4][4];
#pragma unroll
    for (int i = 0; i < 4; i++)
#pragma unroll
        for (int j = 0; j < 4; j++) acc[i][j] = f32x4{0.f, 0.f, 0.f, 0.f};

    const int rbase = lane >> 3;
    const int cSw = ((lane & 7) << 4) ^ (rbase << 4);

    auto STAGE = [&](int buf, int kt) {
        char* base = smem + buf * 32768;
#pragma unroll
        for (int ww = 0; ww < 4; ww++) {
            int w = wid * 4 + ww;
            int r = w * 8 + rbase;
            const unsigned short* srcA = A + (size_t)(m0 + r) * K + kt + (cSw >> 1);
            __builtin_amdgcn_global_load_lds(AS_G(srcA), AS_L(base + w * 1024), 16, 0, 0);
            const unsigned short* srcB = Bt + (size_t)(n0 + r) * K + kt + (cSw >> 1);
            __builtin_amdgcn_global_load_lds(AS_G(srcB), AS_L(base + 16384 + w * 1024), 16, 0, 0);
        }
    };

    const int nk = K >> 6;
    STAGE(0, 0);

    for (int t = 0; t < nk; t++) {
        if (t + 1 < nk) {
            STAGE((t + 1) & 1, (t + 1) << 6);
            asm volatile("s_waitcnt vmcnt(8)" ::: "memory");   // t's 8 loads done
        } else {
            asm volatile("s_waitcnt vmcnt(0)" ::: "memory");
        }
        __builtin_amdgcn_s_barrier();
        char* cbase = smem + (t & 1) * 32768;
#pragma unroll
        for (int ks = 0; ks < 2; ks++) {
            s16x8 af[4], bfr[4];
#pragma unroll
            for (int i = 0; i < 4; i++)
                af[i] = *(const s16x8*)(cbase + swz128(wm * 64 + i * 16 + lr, ks * 64 + g * 16));
#pragma unroll
            for (int j = 0; j < 4; j++)
                bfr[j] = *(const s16x8*)(cbase + 16384 + swz128(wn * 64 + j * 16 + lr, ks * 64 + g * 16));
#pragma unroll
            for (int i = 0; i < 4; i++)
#pragma unroll
                for (int j = 0; j < 4; j++)
                    acc[i][j] = MFMA16x16x32(af[i], bfr[j], acc[i][j]);
        }
        BARRIER_LGKM();
    }

#pragma unroll
    for (int j = 0; j < 4; j++) {
        int c = n0 + wn * 64 + j * 16 + lr;
        float bv = bias[c];
        float cscale = (c < qcols) ? qscale : 1.0f;
        if (Vt != nullptr && c >= 1536) {
            int h = (c - 1536) >> 6, d = (c - 1536) & 63;
#pragma unroll
            for (int i = 0; i < 4; i++) {
                int r0 = m0 + wm * 64 + i * 16 + g * 4;
                int bb = r0 >> 11, t0 = r0 & 2047;
                ushort4 o4;
                o4.x = f2bf(acc[i][j][0] + bv);
                o4.y = f2bf(acc[i][j][1] + bv);
                o4.z = f2bf(acc[i][j][2] + bv);
                o4.w = f2bf(acc[i][j][3] + bv);
                *(ushort4*)(Vt + ((((size_t)bb * 12 + h) * 64 + d) << 11) + t0) = o4;
            }
        } else {
#pragma unroll
            for (int i = 0; i < 4; i++) {
#pragma unroll
                for (int rg = 0; rg < 4; rg++) {
                    int r = m0 + wm * 64 + i * 16 + g * 4 + rg;
                    float val = (acc[i][j][rg] + bv) * cscale;
                    if constexpr (OUT_BF16)
                        ((unsigned short*)Cout)[(size_t)r * ldc + c] = f2bf(val);
                    else
                        ((float*)Cout)[(size_t)r * ldc + c] = val;
                }
            }
        }
    }
}

// ---- causal flash attention: swapped QK^T, KVBLK=128, paired+XCD-clustered ----
// Grid 768: s -> xcd=s&7, i=s>>3 (0..95), grp=xcd*6+(i>>4), qpi=i&15.
// Pair (qpi, 31-qpi) -> every block exactly 33 64-row tile-units (balanced);
// all 16 pairs of one (b,h) on one XCD -> K/V L2-resident.
// KVBLK=128 halves barrier/staging rounds vs 64.
// LDS 48KB: K [128j][64d] 16K | V [64d][128j] 16K | P^T 4 x [16q][128j] 4K.
// Q pre-scaled by 0.125*log2e -> P = exp2(S') directly. No-max softmax.
__global__ __launch_bounds__(256, 2)
void attn_kernel(const unsigned short* __restrict__ qk, const unsigned short* __restrict__ Vt,
                 unsigned short* __restrict__ y) {
    __shared__ char smem[49152];
    const int tid = threadIdx.x, wid = tid >> 6, lane = tid & 63;
    const int g = lane >> 4, lr = lane & 15;
    const int T = 2048;

    const int s = blockIdx.x;
    const int xcd = s & 7, i = s >> 3;
    const int grp = xcd * 6 + (i >> 4);
    const int qpi = i & 15;
    const int h = grp % 12, b = grp / 12;

    const int krow = tid >> 1;          // K: 128 rows, 2 thr/row
    const int kcol = (tid & 1) * 64;    // byte offset in 128B row (64B/thread)
    const int vrow = tid >> 2;          // V: 64 rows, 4 thr/row
    const int vcol = (tid & 3) * 64;    // byte offset in 256B row (64B/thread)

    for (int pp = 0; pp < 2; pp++) {
        const int qt = pp ? (31 - qpi) : qpi;
        const int q0 = qt * 64;

        const unsigned short* qrow = qk + (size_t)(b * T + q0 + wid * 16 + lr) * 1536 + h * 64;
        s16x8 aq[2];
        aq[0] = *(const s16x8*)(qrow + g * 8);
        aq[1] = *(const s16x8*)(qrow + 32 + g * 8);

        float l_acc = 0.f;
        f32x4 o[4];
#pragma unroll
        for (int r = 0; r < 4; r++) o[r] = f32x4{0.f, 0.f, 0.f, 0.f};

        const unsigned short* pkBase = qk + (size_t)(b * T + krow) * 1536 + 768 + h * 64 + (kcol >> 1);
        const unsigned short* pvBase = Vt + ((((size_t)b * 12 + h) * 64 + vrow) << 11) + (vcol >> 1);

        // prologue: tile 0 loads (4+4 x 16B per thread)
        s16x8 kv[8];
#pragma unroll
        for (int c = 0; c < 4; c++) kv[c] = *(const s16x8*)(pkBase + c * 8);
#pragma unroll
        for (int c = 0; c < 4; c++) kv[4 + c] = *(const s16x8*)(pvBase + c * 8);

        const int nt = (qt >> 1) + 1;        // number of 128-wide KV tiles
        for (int t = 0; t < nt; t++) {
            const int j0 = t * 128;
            BARRIER_LGKM();              // prior tile's LDS reads done
#pragma unroll
            for (int c = 0; c < 4; c++)
                *(s16x8*)(smem + swz128(krow, kcol + c * 16)) = kv[c];
#pragma unroll
            for (int c = 0; c < 4; c++)
                *(s16x8*)(smem + 16384 + swz256(vrow, vcol + c * 16)) = kv[4 + c];
            if (t + 1 < nt) {            // issue t+1 loads; in flight through compute(t)
                const unsigned short* pk = pkBase + (size_t)(j0 + 128) * 1536;
#pragma unroll
                for (int c = 0; c < 4; c++) kv[c] = *(const s16x8*)(pk + c * 8);
                const unsigned short* pv = pvBase + (j0 + 128);
#pragma unroll
                for (int c = 0; c < 4; c++) kv[4 + c] = *(const s16x8*)(pv + c * 8);
            }
            BARRIER_LGKM();              // staged tile visible; vmcnt NOT drained

            // S'^T = K Q^T: st[nf][rg] = S[j0 + nf*16+g*4+rg][q0 + wid*16+lr]
            f32x4 st[8];
            __builtin_amdgcn_s_setprio(1);
#pragma unroll
            for (int nf = 0; nf < 8; nf++) {
                f32x4 sf = f32x4{0.f, 0.f, 0.f, 0.f};
#pragma unroll
                for (int ks = 0; ks < 2; ks++) {
                    s16x8 ak = *(const s16x8*)(smem + swz128(nf * 16 + lr, ks * 64 + g * 16));
                    sf = MFMA16x16x32(ak, aq[ks], sf);
                }
                st[nf] = sf;
            }
            __builtin_amdgcn_s_setprio(0);

            // P = exp2(S'); causal mask on the final (diagonal) tile only
            if (t == nt - 1) {
                const int qr = wid * 16 + lr + ((qt & 1) << 6);  // q_rel + 64*(qt&1)
#pragma unroll
                for (int nf = 0; nf < 8; nf++)
#pragma unroll
                    for (int rg = 0; rg < 4; rg++) {
                        float p = exp2f(st[nf][rg]);
                        if (nf * 16 + g * 4 + rg > qr) p = 0.f;
                        st[nf][rg] = p;
                        l_acc += p;
                    }
            } else {
#pragma unroll
                for (int nf = 0; nf < 8; nf++)
#pragma unroll
                    for (int rg = 0; rg < 4; rg++) {
                        float p = exp2f(st[nf][rg]);
                        st[nf][rg] = p;
                        l_acc += p;
                    }
            }

            // P^T -> bf16 via v_cvt_pk -> wave-private LDS [16q][128j]
            char* pbase = smem + 32768 + wid * 4096;
#pragma unroll
            for (int nf = 0; nf < 8; nf++) {
                uint2 dw;
                dw.x = cvt_pk_bf2(st[nf][0], st[nf][1]);
                dw.y = cvt_pk_bf2(st[nf][2], st[nf][3]);
                *(uint2*)(pbase + swz256(lr, nf * 32 + g * 8)) = dw;
            }
            s16x8 pf[4];
#pragma unroll
            for (int ks = 0; ks < 4; ks++)
                pf[ks] = *(const s16x8*)(pbase + swz256(lr, ks * 64 + g * 16));

            // O += P * V
            __builtin_amdgcn_s_setprio(1);
#pragma unroll
            for (int nf = 0; nf < 4; nf++) {
#pragma unroll
                for (int ks = 0; ks < 4; ks++) {
                    s16x8 bv = *(const s16x8*)(smem + 16384 + swz256(nf * 16 + lr, ks * 64 + g * 16));
                    o[nf] = MFMA16x16x32(pf[ks], bv, o[nf]);
                }
            }
            __builtin_amdgcn_s_setprio(0);
        }

        // epilogue: row-sum across g-groups; redistribute 1/l; store
        float l = l_acc;
        l += __shfl_xor(l, 16, 64);
        l += __shfl_xor(l, 32, 64);
        float linv = 1.0f / l;
        float linv_q[4];
#pragma unroll
        for (int rg = 0; rg < 4; rg++)
            linv_q[rg] = __shfl(linv, (lane & 48) | (g * 4 + rg), 64);
#pragma unroll
        for (int nf = 0; nf < 4; nf++) {
#pragma unroll
            for (int rg = 0; rg < 4; rg++) {
                int row = b * T + q0 + wid * 16 + g * 4 + rg;
                int col = h * 64 + nf * 16 + lr;
                y[(size_t)row * 768 + col] = f2bf(o[nf][rg] * linv_q[rg]);
            }
        }
    }
}

extern "C" void kernel_launch(void* const* d_in, const int* in_sizes, int n_in,
                              void* d_out, int out_size, void* d_ws, size_t ws_size,
                              hipStream_t stream) {
    const float* x      = (const float*)d_in[0];
    const float* w_attn = (const float*)d_in[1];
    const float* b_attn = (const float*)d_in[2];
    const float* w_proj = (const float*)d_in[3];
    const float* b_proj = (const float*)d_in[4];

    char* ws = (char*)d_ws;
    unsigned short* qk  = (unsigned short*)(ws);
    unsigned short* Vt  = (unsigned short*)(ws + 25165824);
    unsigned short* wTa = (unsigned short*)(ws + 37748736);
    unsigned short* wTp = (unsigned short*)(ws + 41287680);

    const bool big = ws_size >= (size_t)55050240;
    unsigned short* xb = (unsigned short*)d_out;
    unsigned short* yb = big ? (unsigned short*)(ws + 42467328)
                             : (unsigned short*)((char*)d_out + 12582912);
    float* projOut = big ? (float*)d_out : (float*)ws;

    cvt_f32_bf16<<<2048, 256, 0, stream>>>(x, xb, 8192 * 768);
    transpose_cvt_tiled<<<dim3(72, 24), 256, 0, stream>>>(w_attn, wTa, 768, 2304);
    transpose_cvt_tiled<<<dim3(24, 24), 256, 0, stream>>>(w_proj, wTp, 768, 768);

    // qscale = 0.125 * log2(e): softmax scale and exp->exp2 folded into Q
    gemm_bt<true><<<dim3(18, 64), 256, 0, stream>>>(xb, wTa, b_attn, (void*)qk, Vt,
                                                    8192, 2304, 768, 1536, 768, 0.1803368801111244f);
    attn_kernel<<<768, 256, 0, stream>>>(qk, Vt, yb);
    gemm_bt<false><<<dim3(6, 64), 256, 0, stream>>>(yb, wTp, b_proj, (void*)projOut, nullptr,
                                                    8192, 768, 768, 768, 0, 1.0f);
    if (!big)
        hipMemcpyAsync(d_out, projOut, 25165824, hipMemcpyDeviceToDevice, stream);
}

// Round 12
// 134.341 us; speedup vs baseline: 1.1164x; 1.1164x over previous
//
#include <hip/hip_runtime.h>
#include <hip/hip_bf16.h>

using f32x4 = __attribute__((ext_vector_type(4))) float;
using s16x8 = __attribute__((ext_vector_type(8))) short;

#define MFMA16x16x32(a, b, c) __builtin_amdgcn_mfma_f32_16x16x32_bf16((a), (b), (c), 0, 0, 0)

#define AS_G(p) ((const __attribute__((address_space(1))) void*)(p))
#define AS_L(p) ((__attribute__((address_space(3))) void*)(p))

// barrier with LDS-visibility only: does NOT drain vmcnt
#define BARRIER_LGKM() do { \
    asm volatile("s_waitcnt lgkmcnt(0)" ::: "memory"); \
    __builtin_amdgcn_s_barrier(); \
} while (0)

static __device__ __forceinline__ unsigned short f2bf(float f) {
    unsigned int u = __float_as_uint(f);
    u = (u + 0x7fffu + ((u >> 16) & 1u)) >> 16;
    return (unsigned short)u;
}
static __device__ __forceinline__ unsigned int cvt_pk_bf2(float lo, float hi) {
    unsigned int r;
    asm("v_cvt_pk_bf16_f32 %0, %1, %2" : "=v"(r) : "v"(lo), "v"(hi));
    return r;
}
// swizzled byte offset — used IDENTICALLY on write and read sides
static __device__ __forceinline__ int swz128(int r, int c) { return (r * 128 + c) ^ ((r & 7) << 4); }

// ---- convert fp32 -> bf16 (vectorized) ----
__global__ void cvt_f32_bf16(const float* __restrict__ in, unsigned short* __restrict__ out, int n) {
    int i = (blockIdx.x * blockDim.x + threadIdx.x) * 4;
    int stride = gridDim.x * blockDim.x * 4;
    for (; i < n; i += stride) {
        float4 v = *(const float4*)(in + i);
        ushort4 o;
        o.x = f2bf(v.x); o.y = f2bf(v.y); o.z = f2bf(v.z); o.w = f2bf(v.w);
        *(ushort4*)(out + i) = o;
    }
}

// ---- LDS-tiled transpose+convert: wt[n][k] = bf16(w[k][n]) ----
__global__ __launch_bounds__(256)
void transpose_cvt_tiled(const float* __restrict__ w, unsigned short* __restrict__ wt,
                         int K, int N) {
    __shared__ float tile[32][33];
    const int tid = threadIdx.x;
    const int tx = tid & 31, ty = tid >> 5;
    const int n0 = blockIdx.x * 32, k0 = blockIdx.y * 32;
#pragma unroll
    for (int r = 0; r < 4; r++)
        tile[ty * 4 + r][tx] = w[(size_t)(k0 + ty * 4 + r) * N + n0 + tx];
    __syncthreads();
#pragma unroll
    for (int r = 0; r < 4; r++)
        wt[(size_t)(n0 + ty * 4 + r) * K + k0 + tx] = f2bf(tile[tx][ty * 4 + r]);
}

// ---- GEMM: C[M,N] = A[M,K] * Bt[N,K]^T + bias ----
// 128x128 tile, BK=64, 2-phase dbuf gload_lds staging, counted vmcnt.
template <bool OUT_BF16>
__global__ __launch_bounds__(256, 2)
void gemm_bt(const unsigned short* __restrict__ A, const unsigned short* __restrict__ Bt,
             const float* __restrict__ bias, void* __restrict__ Cout,
             unsigned short* __restrict__ Vt,
             int M, int N, int K, int ldc, int qcols, float qscale) {
    __shared__ char smem[65536];
    const int tid = threadIdx.x, wid = tid >> 6, lane = tid & 63;
    const int g = lane >> 4, lr = lane & 15;
    const int m0 = blockIdx.y * 128, n0 = blockIdx.x * 128;
    const int wm = wid >> 1, wn = wid & 1;

    f32x4 acc[4][4];
#pragma unroll
    for (int i = 0; i < 4; i++)
#pragma unroll
        for (int j = 0; j < 4; j++) acc[i][j] = f32x4{0.f, 0.f, 0.f, 0.f};

    const int rbase = lane >> 3;
    const int cSw = ((lane & 7) << 4) ^ (rbase << 4);

    auto STAGE = [&](int buf, int kt) {
        char* base = smem + buf * 32768;
#pragma unroll
        for (int ww = 0; ww < 4; ww++) {
            int w = wid * 4 + ww;
            int r = w * 8 + rbase;
            const unsigned short* srcA = A + (size_t)(m0 + r) * K + kt + (cSw >> 1);
            __builtin_amdgcn_global_load_lds(AS_G(srcA), AS_L(base + w * 1024), 16, 0, 0);
            const unsigned short* srcB = Bt + (size_t)(n0 + r) * K + kt + (cSw >> 1);
            __builtin_amdgcn_global_load_lds(AS_G(srcB), AS_L(base + 16384 + w * 1024), 16, 0, 0);
        }
    };

    const int nk = K >> 6;
    STAGE(0, 0);

    for (int t = 0; t < nk; t++) {
        if (t + 1 < nk) {
            STAGE((t + 1) & 1, (t + 1) << 6);
            asm volatile("s_waitcnt vmcnt(8)" ::: "memory");   // t's 8 loads done
        } else {
            asm volatile("s_waitcnt vmcnt(0)" ::: "memory");
        }
        __builtin_amdgcn_s_barrier();
        char* cbase = smem + (t & 1) * 32768;
#pragma unroll
        for (int ks = 0; ks < 2; ks++) {
            s16x8 af[4], bfr[4];
#pragma unroll
            for (int i = 0; i < 4; i++)
                af[i] = *(const s16x8*)(cbase + swz128(wm * 64 + i * 16 + lr, ks * 64 + g * 16));
#pragma unroll
            for (int j = 0; j < 4; j++)
                bfr[j] = *(const s16x8*)(cbase + 16384 + swz128(wn * 64 + j * 16 + lr, ks * 64 + g * 16));
#pragma unroll
            for (int i = 0; i < 4; i++)
#pragma unroll
                for (int j = 0; j < 4; j++)
                    acc[i][j] = MFMA16x16x32(af[i], bfr[j], acc[i][j]);
        }
        BARRIER_LGKM();
    }

#pragma unroll
    for (int j = 0; j < 4; j++) {
        int c = n0 + wn * 64 + j * 16 + lr;
        float bv = bias[c];
        float cscale = (c < qcols) ? qscale : 1.0f;
        if (Vt != nullptr && c >= 1536) {
            int h = (c - 1536) >> 6, d = (c - 1536) & 63;
#pragma unroll
            for (int i = 0; i < 4; i++) {
                int r0 = m0 + wm * 64 + i * 16 + g * 4;
                int bb = r0 >> 11, t0 = r0 & 2047;
                ushort4 o4;
                o4.x = f2bf(acc[i][j][0] + bv);
                o4.y = f2bf(acc[i][j][1] + bv);
                o4.z = f2bf(acc[i][j][2] + bv);
                o4.w = f2bf(acc[i][j][3] + bv);
                *(ushort4*)(Vt + ((((size_t)bb * 12 + h) * 64 + d) << 11) + t0) = o4;
            }
        } else {
#pragma unroll
            for (int i = 0; i < 4; i++) {
#pragma unroll
                for (int rg = 0; rg < 4; rg++) {
                    int r = m0 + wm * 64 + i * 16 + g * 4 + rg;
                    float val = (acc[i][j][rg] + bv) * cscale;
                    if constexpr (OUT_BF16)
                        ((unsigned short*)Cout)[(size_t)r * ldc + c] = f2bf(val);
                    else
                        ((float*)Cout)[(size_t)r * ldc + c] = val;
                }
            }
        }
    }
}

// ---- causal flash attention: swapped QK^T, KVBLK=64, dbuf K/V (1 barrier/tile),
// paired + XCD-clustered.
// Grid 768: s -> xcd=s&7, i=s>>3 (0..95), grp=xcd*6+(i>>4), qpi=i&15.
// Pair (qpi, 31-qpi): every block exactly 33 tile-units (balanced); all 16
// pairs of one (b,h) on one XCD -> K/V L2-resident (FETCH 182->18.5 MB).
// LDS 40KB: Kbuf[2] 2x8K | Vbuf[2] 2x8K at +16K | P^T 4x2K at +32K.
// Double-buffer: compute(t) reads buf[t&1] while writes for t+1 land in
// buf[(t+1)&1] -> ONE lgkm-barrier per tile (vs 2). Loads for t+2 issued
// after the writes; vmcnt never drained in-loop.
// Q pre-scaled by 0.125*log2e -> P = exp2(S'). No-max softmax.
__global__ __launch_bounds__(256, 2)
void attn_kernel(const unsigned short* __restrict__ qk, const unsigned short* __restrict__ Vt,
                 unsigned short* __restrict__ y) {
    __shared__ char smem[40960];
    const int tid = threadIdx.x, wid = tid >> 6, lane = tid & 63;
    const int g = lane >> 4, lr = lane & 15;
    const int T = 2048;

    const int s = blockIdx.x;
    const int xcd = s & 7, i = s >> 3;
    const int grp = xcd * 6 + (i >> 4);
    const int qpi = i & 15;
    const int h = grp % 12, b = grp / 12;

    const int krow = tid >> 2;          // staging: 64 rows, 4 threads/row
    const int kcol = (tid & 3) * 32;    // byte offset in 128B row

    for (int pp = 0; pp < 2; pp++) {
        const int qt = pp ? (31 - qpi) : qpi;
        const int q0 = qt * 64;

        const unsigned short* qrow = qk + (size_t)(b * T + q0 + wid * 16 + lr) * 1536 + h * 64;
        s16x8 aq[2];
        aq[0] = *(const s16x8*)(qrow + g * 8);
        aq[1] = *(const s16x8*)(qrow + 32 + g * 8);

        float l_acc = 0.f;
        f32x4 o[4];
#pragma unroll
        for (int r = 0; r < 4; r++) o[r] = f32x4{0.f, 0.f, 0.f, 0.f};

        const unsigned short* pkBase = qk + (size_t)(b * T + krow) * 1536 + 768 + h * 64 + (kcol >> 1);
        const unsigned short* pvBase = Vt + ((((size_t)b * 12 + h) * 64 + krow) << 11) + (kcol >> 1);

        const int nt = qt + 1;

        // prologue: load tile 0, write into buf0, issue loads for tile 1
        s16x8 k0 = *(const s16x8*)(pkBase);
        s16x8 k1 = *(const s16x8*)(pkBase + 8);
        s16x8 v0 = *(const s16x8*)(pvBase);
        s16x8 v1 = *(const s16x8*)(pvBase + 8);
        *(s16x8*)(smem + swz128(krow, kcol)) = k0;
        *(s16x8*)(smem + swz128(krow, kcol + 16)) = k1;
        *(s16x8*)(smem + 16384 + swz128(krow, kcol)) = v0;
        *(s16x8*)(smem + 16384 + swz128(krow, kcol + 16)) = v1;
        if (nt > 1) {
            const unsigned short* pk = pkBase + (size_t)64 * 1536;
            k0 = *(const s16x8*)(pk);
            k1 = *(const s16x8*)(pk + 8);
            const unsigned short* pv = pvBase + 64;
            v0 = *(const s16x8*)(pv);
            v1 = *(const s16x8*)(pv + 8);
        }
        BARRIER_LGKM();

        for (int t = 0; t < nt; t++) {
            char* kbase = smem + (t & 1) * 8192;
            char* vbase = smem + 16384 + (t & 1) * 8192;

            // S'^T = K Q^T (Q pre-scaled by 0.125*log2e)
            f32x4 st[4];
            __builtin_amdgcn_s_setprio(1);
#pragma unroll
            for (int nf = 0; nf < 4; nf++) {
                f32x4 sf = f32x4{0.f, 0.f, 0.f, 0.f};
#pragma unroll
                for (int ks = 0; ks < 2; ks++) {
                    int jj = nf * 16 + lr;
                    s16x8 ak = *(const s16x8*)(kbase + swz128(jj, (ks * 32 + g * 8) * 2));
                    sf = MFMA16x16x32(ak, aq[ks], sf);
                }
                st[nf] = sf;
            }
            __builtin_amdgcn_s_setprio(0);

            // P = exp2(S'), causal mask on the diagonal (final) tile
            const bool diag = (t == nt - 1);
            const int q_rel = wid * 16 + lr;
#pragma unroll
            for (int nf = 0; nf < 4; nf++) {
#pragma unroll
                for (int rg = 0; rg < 4; rg++) {
                    float p = exp2f(st[nf][rg]);
                    if (diag && (nf * 16 + g * 4 + rg > q_rel)) p = 0.f;
                    st[nf][rg] = p;
                    l_acc += p;
                }
            }

            // P^T -> bf16 via v_cvt_pk -> wave-private LDS
            char* pbase = smem + 32768 + wid * 2048;
#pragma unroll
            for (int nf = 0; nf < 4; nf++) {
                uint2 dw;
                dw.x = cvt_pk_bf2(st[nf][0], st[nf][1]);
                dw.y = cvt_pk_bf2(st[nf][2], st[nf][3]);
                *(uint2*)(pbase + swz128(lr, nf * 32 + g * 8)) = dw;
            }
            s16x8 pf[2];
#pragma unroll
            for (int ks = 0; ks < 2; ks++)
                pf[ks] = *(const s16x8*)(pbase + swz128(lr, ks * 64 + g * 16));

            // O += P * V
            __builtin_amdgcn_s_setprio(1);
#pragma unroll
            for (int nf = 0; nf < 4; nf++) {
#pragma unroll
                for (int ks = 0; ks < 2; ks++) {
                    int d = nf * 16 + lr;
                    s16x8 bv = *(const s16x8*)(vbase + swz128(d, ks * 64 + g * 16));
                    o[nf] = MFMA16x16x32(pf[ks], bv, o[nf]);
                }
            }
            __builtin_amdgcn_s_setprio(0);

            // write tile t+1 into the OTHER buffer (no conflict with readers
            // of buf[t&1]); then issue loads for t+2
            if (t + 1 < nt) {
                char* kn = smem + ((t + 1) & 1) * 8192;
                char* vn = smem + 16384 + ((t + 1) & 1) * 8192;
                *(s16x8*)(kn + swz128(krow, kcol)) = k0;
                *(s16x8*)(kn + swz128(krow, kcol + 16)) = k1;
                *(s16x8*)(vn + swz128(krow, kcol)) = v0;
                *(s16x8*)(vn + swz128(krow, kcol + 16)) = v1;
                if (t + 2 < nt) {
                    const unsigned short* pk = pkBase + (size_t)(t + 2) * 64 * 1536;
                    k0 = *(const s16x8*)(pk);
                    k1 = *(const s16x8*)(pk + 8);
                    const unsigned short* pv = pvBase + (t + 2) * 64;
                    v0 = *(const s16x8*)(pv);
                    v1 = *(const s16x8*)(pv + 8);
                }
            }
            BARRIER_LGKM();              // single barrier per tile
        }

        // epilogue: row-sum across g-groups; redistribute 1/l; store
        float l = l_acc;
        l += __shfl_xor(l, 16, 64);
        l += __shfl_xor(l, 32, 64);
        float linv = 1.0f / l;
        float linv_q[4];
#pragma unroll
        for (int rg = 0; rg < 4; rg++)
            linv_q[rg] = __shfl(linv, (lane & 48) | (g * 4 + rg), 64);
#pragma unroll
        for (int nf = 0; nf < 4; nf++) {
#pragma unroll
            for (int rg = 0; rg < 4; rg++) {
                int row = b * T + q0 + wid * 16 + g * 4 + rg;
                int col = h * 64 + nf * 16 + lr;
                y[(size_t)row * 768 + col] = f2bf(o[nf][rg] * linv_q[rg]);
            }
        }
    }
}

extern "C" void kernel_launch(void* const* d_in, const int* in_sizes, int n_in,
                              void* d_out, int out_size, void* d_ws, size_t ws_size,
                              hipStream_t stream) {
    const float* x      = (const float*)d_in[0];
    const float* w_attn = (const float*)d_in[1];
    const float* b_attn = (const float*)d_in[2];
    const float* w_proj = (const float*)d_in[3];
    const float* b_proj = (const float*)d_in[4];

    char* ws = (char*)d_ws;
    unsigned short* qk  = (unsigned short*)(ws);
    unsigned short* Vt  = (unsigned short*)(ws + 25165824);
    unsigned short* wTa = (unsigned short*)(ws + 37748736);
    unsigned short* wTp = (unsigned short*)(ws + 41287680);

    const bool big = ws_size >= (size_t)55050240;
    unsigned short* xb = (unsigned short*)d_out;
    unsigned short* yb = big ? (unsigned short*)(ws + 42467328)
                             : (unsigned short*)((char*)d_out + 12582912);
    float* projOut = big ? (float*)d_out : (float*)ws;

    cvt_f32_bf16<<<2048, 256, 0, stream>>>(x, xb, 8192 * 768);
    transpose_cvt_tiled<<<dim3(72, 24), 256, 0, stream>>>(w_attn, wTa, 768, 2304);
    transpose_cvt_tiled<<<dim3(24, 24), 256, 0, stream>>>(w_proj, wTp, 768, 768);

    // qscale = 0.125 * log2(e): softmax scale and exp->exp2 folded into Q
    gemm_bt<true><<<dim3(18, 64), 256, 0, stream>>>(xb, wTa, b_attn, (void*)qk, Vt,
                                                    8192, 2304, 768, 1536, 768, 0.1803368801111244f);
    attn_kernel<<<768, 256, 0, stream>>>(qk, Vt, yb);
    gemm_bt<false><<<dim3(6, 64), 256, 0, stream>>>(yb, wTp, b_proj, (void*)projOut, nullptr,
                                                    8192, 768, 768, 768, 0, 1.0f);
    if (!big)
        hipMemcpyAsync(d_out, projOut, 25165824, hipMemcpyDeviceToDevice, stream);
}

// Round 13
// 132.160 us; speedup vs baseline: 1.1348x; 1.0165x over previous
//
#include <hip/hip_runtime.h>
#include <hip/hip_bf16.h>

using f32x4 = __attribute__((ext_vector_type(4))) float;
using s16x8 = __attribute__((ext_vector_type(8))) short;

#define MFMA16x16x32(a, b, c) __builtin_amdgcn_mfma_f32_16x16x32_bf16((a), (b), (c), 0, 0, 0)

#define AS_G(p) ((const __attribute__((address_space(1))) void*)(p))
#define AS_L(p) ((__attribute__((address_space(3))) void*)(p))

// barrier with LDS-visibility only: does NOT drain vmcnt
#define BARRIER_LGKM() do { \
    asm volatile("s_waitcnt lgkmcnt(0)" ::: "memory"); \
    __builtin_amdgcn_s_barrier(); \
} while (0)

static __device__ __forceinline__ unsigned short f2bf(float f) {
    unsigned int u = __float_as_uint(f);
    u = (u + 0x7fffu + ((u >> 16) & 1u)) >> 16;
    return (unsigned short)u;
}
static __device__ __forceinline__ unsigned int cvt_pk_bf2(float lo, float hi) {
    unsigned int r;
    asm("v_cvt_pk_bf16_f32 %0, %1, %2" : "=v"(r) : "v"(lo), "v"(hi));
    return r;
}
// swizzled byte offset — used IDENTICALLY on write and read sides
static __device__ __forceinline__ int swz128(int r, int c) { return (r * 128 + c) ^ ((r & 7) << 4); }

// ---- fused prologue: x->bf16 convert + both weight transposes ----
// blocks [0,2048): cvt x; [2048,3776): w_attn^T; [3776,4352): w_proj^T
__global__ __launch_bounds__(256)
void prologue_kernel(const float* __restrict__ x, unsigned short* __restrict__ xb,
                     const float* __restrict__ w_attn, unsigned short* __restrict__ wTa,
                     const float* __restrict__ w_proj, unsigned short* __restrict__ wTp) {
    __shared__ float tile[32][33];
    const int bid = blockIdx.x, tid = threadIdx.x;
    if (bid < 2048) {
        const int n = 8192 * 768;
        int i = (bid * 256 + tid) * 4;
        const int stride = 2048 * 256 * 4;
        for (; i < n; i += stride) {
            float4 v = *(const float4*)(x + i);
            ushort4 o;
            o.x = f2bf(v.x); o.y = f2bf(v.y); o.z = f2bf(v.z); o.w = f2bf(v.w);
            *(ushort4*)(xb + i) = o;
        }
    } else {
        const float* w; unsigned short* wt; int K, N, bx, by;
        if (bid < 3776) {
            int id = bid - 2048; w = w_attn; wt = wTa; K = 768; N = 2304;
            bx = id % 72; by = id / 72;
        } else {
            int id = bid - 3776; w = w_proj; wt = wTp; K = 768; N = 768;
            bx = id % 24; by = id / 24;
        }
        const int tx = tid & 31, ty = tid >> 5;
        const int n0 = bx * 32, k0 = by * 32;
#pragma unroll
        for (int r = 0; r < 4; r++)
            tile[ty * 4 + r][tx] = w[(size_t)(k0 + ty * 4 + r) * N + n0 + tx];
        __syncthreads();
#pragma unroll
        for (int r = 0; r < 4; r++)
            wt[(size_t)(n0 + ty * 4 + r) * K + k0 + tx] = f2bf(tile[tx][ty * 4 + r]);
    }
}

// ---- GEMM: C[M,N] = A[M,K] * Bt[N,K]^T + bias ----
// 128x128 tile, BK=64, 2-phase dbuf gload_lds staging, counted vmcnt.
template <bool OUT_BF16>
__global__ __launch_bounds__(256, 2)
void gemm_bt(const unsigned short* __restrict__ A, const unsigned short* __restrict__ Bt,
             const float* __restrict__ bias, void* __restrict__ Cout,
             unsigned short* __restrict__ Vt,
             int M, int N, int K, int ldc, int qcols, float qscale) {
    __shared__ char smem[65536];
    const int tid = threadIdx.x, wid = tid >> 6, lane = tid & 63;
    const int g = lane >> 4, lr = lane & 15;
    const int m0 = blockIdx.y * 128, n0 = blockIdx.x * 128;
    const int wm = wid >> 1, wn = wid & 1;

    f32x4 acc[4][4];
#pragma unroll
    for (int i = 0; i < 4; i++)
#pragma unroll
        for (int j = 0; j < 4; j++) acc[i][j] = f32x4{0.f, 0.f, 0.f, 0.f};

    const int rbase = lane >> 3;
    const int cSw = ((lane & 7) << 4) ^ (rbase << 4);

    auto STAGE = [&](int buf, int kt) {
        char* base = smem + buf * 32768;
#pragma unroll
        for (int ww = 0; ww < 4; ww++) {
            int w = wid * 4 + ww;
            int r = w * 8 + rbase;
            const unsigned short* srcA = A + (size_t)(m0 + r) * K + kt + (cSw >> 1);
            __builtin_amdgcn_global_load_lds(AS_G(srcA), AS_L(base + w * 1024), 16, 0, 0);
            const unsigned short* srcB = Bt + (size_t)(n0 + r) * K + kt + (cSw >> 1);
            __builtin_amdgcn_global_load_lds(AS_G(srcB), AS_L(base + 16384 + w * 1024), 16, 0, 0);
        }
    };

    const int nk = K >> 6;
    STAGE(0, 0);

    for (int t = 0; t < nk; t++) {
        if (t + 1 < nk) {
            STAGE((t + 1) & 1, (t + 1) << 6);
            asm volatile("s_waitcnt vmcnt(8)" ::: "memory");   // t's 8 loads done
        } else {
            asm volatile("s_waitcnt vmcnt(0)" ::: "memory");
        }
        __builtin_amdgcn_s_barrier();
        char* cbase = smem + (t & 1) * 32768;
#pragma unroll
        for (int ks = 0; ks < 2; ks++) {
            s16x8 af[4], bfr[4];
#pragma unroll
            for (int i = 0; i < 4; i++)
                af[i] = *(const s16x8*)(cbase + swz128(wm * 64 + i * 16 + lr, ks * 64 + g * 16));
#pragma unroll
            for (int j = 0; j < 4; j++)
                bfr[j] = *(const s16x8*)(cbase + 16384 + swz128(wn * 64 + j * 16 + lr, ks * 64 + g * 16));
#pragma unroll
            for (int i = 0; i < 4; i++)
#pragma unroll
                for (int j = 0; j < 4; j++)
                    acc[i][j] = MFMA16x16x32(af[i], bfr[j], acc[i][j]);
        }
        BARRIER_LGKM();
    }

#pragma unroll
    for (int j = 0; j < 4; j++) {
        int c = n0 + wn * 64 + j * 16 + lr;
        float bv = bias[c];
        float cscale = (c < qcols) ? qscale : 1.0f;
        if (Vt != nullptr && c >= 1536) {
            int h = (c - 1536) >> 6, d = (c - 1536) & 63;
#pragma unroll
            for (int i = 0; i < 4; i++) {
                int r0 = m0 + wm * 64 + i * 16 + g * 4;
                int bb = r0 >> 11, t0 = r0 & 2047;
                ushort4 o4;
                o4.x = f2bf(acc[i][j][0] + bv);
                o4.y = f2bf(acc[i][j][1] + bv);
                o4.z = f2bf(acc[i][j][2] + bv);
                o4.w = f2bf(acc[i][j][3] + bv);
                *(ushort4*)(Vt + ((((size_t)bb * 12 + h) * 64 + d) << 11) + t0) = o4;
            }
        } else {
#pragma unroll
            for (int i = 0; i < 4; i++) {
#pragma unroll
                for (int rg = 0; rg < 4; rg++) {
                    int r = m0 + wm * 64 + i * 16 + g * 4 + rg;
                    float val = (acc[i][j][rg] + bv) * cscale;
                    if constexpr (OUT_BF16)
                        ((unsigned short*)Cout)[(size_t)r * ldc + c] = f2bf(val);
                    else
                        ((float*)Cout)[(size_t)r * ldc + c] = val;
                }
            }
        }
    }
}

// ---- causal flash attention: swapped QK^T, MERGED q-tile pair, dbuf K/V ----
// Grid 768: s -> xcd=s&7, i=s>>3, grp=xcd*6+(i>>4), qpi=i&15 (XCD-clustered:
// all 16 pair-blocks of one (b,h) on one XCD -> K/V L2-resident).
// Pair (qtA=qpi, qtB=31-qpi) processed in ONE K/V sweep over tiles 0..qtB:
// shared tiles (t<=qtA) compute BOTH q-tiles between one barrier pair ->
// barrier/staging count drops 33 -> 32-qpi while compute stays 33 (balanced).
// LDS 40KB: Kbuf[2] 2x8K | Vbuf[2] 2x8K @+16K | P^T 4x2K @+32K.
// Q pre-scaled by 0.125*log2e -> P = exp2(S'). No-max softmax.
__global__ __launch_bounds__(256, 2)
void attn_kernel(const unsigned short* __restrict__ qk, const unsigned short* __restrict__ Vt,
                 unsigned short* __restrict__ y) {
    __shared__ char smem[40960];
    const int tid = threadIdx.x, wid = tid >> 6, lane = tid & 63;
    const int g = lane >> 4, lr = lane & 15;
    const int T = 2048;

    const int s = blockIdx.x;
    const int xcd = s & 7, i = s >> 3;
    const int grp = xcd * 6 + (i >> 4);
    const int qpi = i & 15;
    const int h = grp % 12, b = grp / 12;
    const int qtA = qpi, qtB = 31 - qpi;
    const int q0A = qtA * 64, q0B = qtB * 64;

    const int krow = tid >> 2;          // staging: 64 rows, 4 threads/row
    const int kcol = (tid & 3) * 32;    // byte offset in 128B row

    // Q fragments for both q-tiles (B-operand): col q=lr, d elems ks*32+g*8+e
    const unsigned short* qrowA = qk + (size_t)(b * T + q0A + wid * 16 + lr) * 1536 + h * 64;
    const unsigned short* qrowB = qk + (size_t)(b * T + q0B + wid * 16 + lr) * 1536 + h * 64;
    s16x8 aqA[2], aqB[2];
    aqA[0] = *(const s16x8*)(qrowA + g * 8);
    aqA[1] = *(const s16x8*)(qrowA + 32 + g * 8);
    aqB[0] = *(const s16x8*)(qrowB + g * 8);
    aqB[1] = *(const s16x8*)(qrowB + 32 + g * 8);

    float lA = 0.f, lB = 0.f;
    f32x4 oA[4], oB[4];
#pragma unroll
    for (int r = 0; r < 4; r++) { oA[r] = f32x4{0.f, 0.f, 0.f, 0.f}; oB[r] = f32x4{0.f, 0.f, 0.f, 0.f}; }

    const unsigned short* pkBase = qk + (size_t)(b * T + krow) * 1536 + 768 + h * 64 + (kcol >> 1);
    const unsigned short* pvBase = Vt + ((((size_t)b * 12 + h) * 64 + krow) << 11) + (kcol >> 1);

    const int ntA = qtA + 1, ntB = qtB + 1;

    // prologue: load tile 0 -> buf0; issue loads for tile 1
    s16x8 k0 = *(const s16x8*)(pkBase);
    s16x8 k1 = *(const s16x8*)(pkBase + 8);
    s16x8 v0 = *(const s16x8*)(pvBase);
    s16x8 v1 = *(const s16x8*)(pvBase + 8);
    *(s16x8*)(smem + swz128(krow, kcol)) = k0;
    *(s16x8*)(smem + swz128(krow, kcol + 16)) = k1;
    *(s16x8*)(smem + 16384 + swz128(krow, kcol)) = v0;
    *(s16x8*)(smem + 16384 + swz128(krow, kcol + 16)) = v1;
    if (ntB > 1) {
        const unsigned short* pk = pkBase + (size_t)64 * 1536;
        k0 = *(const s16x8*)(pk);
        k1 = *(const s16x8*)(pk + 8);
        const unsigned short* pv = pvBase + 64;
        v0 = *(const s16x8*)(pv);
        v1 = *(const s16x8*)(pv + 8);
    }
    BARRIER_LGKM();

    char* const pbase = smem + 32768 + wid * 2048;
    const int q_rel = wid * 16 + lr;

    for (int t = 0; t < ntB; t++) {
        char* kbase = smem + (t & 1) * 8192;
        char* vbase = smem + 16384 + (t & 1) * 8192;

        // ---------------- q-tile B (always active) ----------------
        {
            f32x4 st[4];
            __builtin_amdgcn_s_setprio(1);
#pragma unroll
            for (int nf = 0; nf < 4; nf++) {
                f32x4 sf = f32x4{0.f, 0.f, 0.f, 0.f};
#pragma unroll
                for (int ks = 0; ks < 2; ks++) {
                    s16x8 ak = *(const s16x8*)(kbase + swz128(nf * 16 + lr, (ks * 32 + g * 8) * 2));
                    sf = MFMA16x16x32(ak, aqB[ks], sf);
                }
                st[nf] = sf;
            }
            __builtin_amdgcn_s_setprio(0);

            const bool diag = (t == ntB - 1);
#pragma unroll
            for (int nf = 0; nf < 4; nf++)
#pragma unroll
                for (int rg = 0; rg < 4; rg++) {
                    float p = exp2f(st[nf][rg]);
                    if (diag && (nf * 16 + g * 4 + rg > q_rel)) p = 0.f;
                    st[nf][rg] = p;
                    lB += p;
                }

#pragma unroll
            for (int nf = 0; nf < 4; nf++) {
                uint2 dw;
                dw.x = cvt_pk_bf2(st[nf][0], st[nf][1]);
                dw.y = cvt_pk_bf2(st[nf][2], st[nf][3]);
                *(uint2*)(pbase + swz128(lr, nf * 32 + g * 8)) = dw;
            }
            s16x8 pf[2];
#pragma unroll
            for (int ks = 0; ks < 2; ks++)
                pf[ks] = *(const s16x8*)(pbase + swz128(lr, ks * 64 + g * 16));

            __builtin_amdgcn_s_setprio(1);
#pragma unroll
            for (int nf = 0; nf < 4; nf++) {
#pragma unroll
                for (int ks = 0; ks < 2; ks++) {
                    s16x8 bv = *(const s16x8*)(vbase + swz128(nf * 16 + lr, ks * 64 + g * 16));
                    oB[nf] = MFMA16x16x32(pf[ks], bv, oB[nf]);
                }
            }
            __builtin_amdgcn_s_setprio(0);
        }

        // ---------------- q-tile A (shared tiles only) ----------------
        if (t < ntA) {
            f32x4 st[4];
            __builtin_amdgcn_s_setprio(1);
#pragma unroll
            for (int nf = 0; nf < 4; nf++) {
                f32x4 sf = f32x4{0.f, 0.f, 0.f, 0.f};
#pragma unroll
                for (int ks = 0; ks < 2; ks++) {
                    s16x8 ak = *(const s16x8*)(kbase + swz128(nf * 16 + lr, (ks * 32 + g * 8) * 2));
                    sf = MFMA16x16x32(ak, aqA[ks], sf);
                }
                st[nf] = sf;
            }
            __builtin_amdgcn_s_setprio(0);

            const bool diag = (t == ntA - 1);
#pragma unroll
            for (int nf = 0; nf < 4; nf++)
#pragma unroll
                for (int rg = 0; rg < 4; rg++) {
                    float p = exp2f(st[nf][rg]);
                    if (diag && (nf * 16 + g * 4 + rg > q_rel)) p = 0.f;
                    st[nf][rg] = p;
                    lA += p;
                }

#pragma unroll
            for (int nf = 0; nf < 4; nf++) {
                uint2 dw;
                dw.x = cvt_pk_bf2(st[nf][0], st[nf][1]);
                dw.y = cvt_pk_bf2(st[nf][2], st[nf][3]);
                *(uint2*)(pbase + swz128(lr, nf * 32 + g * 8)) = dw;
            }
            s16x8 pf[2];
#pragma unroll
            for (int ks = 0; ks < 2; ks++)
                pf[ks] = *(const s16x8*)(pbase + swz128(lr, ks * 64 + g * 16));

            __builtin_amdgcn_s_setprio(1);
#pragma unroll
            for (int nf = 0; nf < 4; nf++) {
#pragma unroll
                for (int ks = 0; ks < 2; ks++) {
                    s16x8 bv = *(const s16x8*)(vbase + swz128(nf * 16 + lr, ks * 64 + g * 16));
                    oA[nf] = MFMA16x16x32(pf[ks], bv, oA[nf]);
                }
            }
            __builtin_amdgcn_s_setprio(0);
        }

        // stage tile t+1 into the other buffer; issue loads for t+2
        if (t + 1 < ntB) {
            char* kn = smem + ((t + 1) & 1) * 8192;
            char* vn = smem + 16384 + ((t + 1) & 1) * 8192;
            *(s16x8*)(kn + swz128(krow, kcol)) = k0;
            *(s16x8*)(kn + swz128(krow, kcol + 16)) = k1;
            *(s16x8*)(vn + swz128(krow, kcol)) = v0;
            *(s16x8*)(vn + swz128(krow, kcol + 16)) = v1;
            if (t + 2 < ntB) {
                const unsigned short* pk = pkBase + (size_t)(t + 2) * 64 * 1536;
                k0 = *(const s16x8*)(pk);
                k1 = *(const s16x8*)(pk + 8);
                const unsigned short* pv = pvBase + (t + 2) * 64;
                v0 = *(const s16x8*)(pv);
                v1 = *(const s16x8*)(pv + 8);
            }
        }
        BARRIER_LGKM();              // single barrier per tile
    }

    // epilogue: per q-tile row-sum across g-groups; redistribute 1/l; store
#pragma unroll
    for (int which = 0; which < 2; which++) {
        float l = which ? lB : lA;
        l += __shfl_xor(l, 16, 64);
        l += __shfl_xor(l, 32, 64);
        float linv = 1.0f / l;
        float linv_q[4];
#pragma unroll
        for (int rg = 0; rg < 4; rg++)
            linv_q[rg] = __shfl(linv, (lane & 48) | (g * 4 + rg), 64);
        const int q0 = which ? q0B : q0A;
        f32x4* o = which ? oB : oA;
#pragma unroll
        for (int nf = 0; nf < 4; nf++) {
#pragma unroll
            for (int rg = 0; rg < 4; rg++) {
                int row = b * T + q0 + wid * 16 + g * 4 + rg;
                int col = h * 64 + nf * 16 + lr;
                y[(size_t)row * 768 + col] = f2bf(o[nf][rg] * linv_q[rg]);
            }
        }
    }
}

extern "C" void kernel_launch(void* const* d_in, const int* in_sizes, int n_in,
                              void* d_out, int out_size, void* d_ws, size_t ws_size,
                              hipStream_t stream) {
    const float* x      = (const float*)d_in[0];
    const float* w_attn = (const float*)d_in[1];
    const float* b_attn = (const float*)d_in[2];
    const float* w_proj = (const float*)d_in[3];
    const float* b_proj = (const float*)d_in[4];

    char* ws = (char*)d_ws;
    unsigned short* qk  = (unsigned short*)(ws);
    unsigned short* Vt  = (unsigned short*)(ws + 25165824);
    unsigned short* wTa = (unsigned short*)(ws + 37748736);
    unsigned short* wTp = (unsigned short*)(ws + 41287680);

    const bool big = ws_size >= (size_t)55050240;
    unsigned short* xb = (unsigned short*)d_out;
    unsigned short* yb = big ? (unsigned short*)(ws + 42467328)
                             : (unsigned short*)((char*)d_out + 12582912);
    float* projOut = big ? (float*)d_out : (float*)ws;

    prologue_kernel<<<4352, 256, 0, stream>>>(x, xb, w_attn, wTa, w_proj, wTp);

    // qscale = 0.125 * log2(e): softmax scale and exp->exp2 folded into Q
    gemm_bt<true><<<dim3(18, 64), 256, 0, stream>>>(xb, wTa, b_attn, (void*)qk, Vt,
                                                    8192, 2304, 768, 1536, 768, 0.1803368801111244f);
    attn_kernel<<<768, 256, 0, stream>>>(qk, Vt, yb);
    gemm_bt<false><<<dim3(6, 64), 256, 0, stream>>>(yb, wTp, b_proj, (void*)projOut, nullptr,
                                                    8192, 768, 768, 768, 0, 1.0f);
    if (!big)
        hipMemcpyAsync(d_out, projOut, 25165824, hipMemcpyDeviceToDevice, stream);
}

// Round 14
// 123.827 us; speedup vs baseline: 1.2112x; 1.0673x over previous
//
#include <hip/hip_runtime.h>
#include <hip/hip_bf16.h>

using f32x4 = __attribute__((ext_vector_type(4))) float;
using s16x8 = __attribute__((ext_vector_type(8))) short;

#define MFMA16x16x32(a, b, c) __builtin_amdgcn_mfma_f32_16x16x32_bf16((a), (b), (c), 0, 0, 0)

#define AS_G(p) ((const __attribute__((address_space(1))) void*)(p))
#define AS_L(p) ((__attribute__((address_space(3))) void*)(p))

// barrier with LDS-visibility only: does NOT drain vmcnt
#define BARRIER_LGKM() do { \
    asm volatile("s_waitcnt lgkmcnt(0)" ::: "memory"); \
    __builtin_amdgcn_s_barrier(); \
} while (0)

static __device__ __forceinline__ unsigned short f2bf(float f) {
    unsigned int u = __float_as_uint(f);
    u = (u + 0x7fffu + ((u >> 16) & 1u)) >> 16;
    return (unsigned short)u;
}
static __device__ __forceinline__ unsigned int cvt_pk_bf2(float lo, float hi) {
    unsigned int r;
    asm("v_cvt_pk_bf16_f32 %0, %1, %2" : "=v"(r) : "v"(lo), "v"(hi));
    return r;
}
// swizzled byte offset — used IDENTICALLY on write and read sides
static __device__ __forceinline__ int swz128(int r, int c) { return (r * 128 + c) ^ ((r & 7) << 4); }

// ---- fused prologue: x->bf16 convert + both weight transposes ----
__global__ __launch_bounds__(256)
void prologue_kernel(const float* __restrict__ x, unsigned short* __restrict__ xb,
                     const float* __restrict__ w_attn, unsigned short* __restrict__ wTa,
                     const float* __restrict__ w_proj, unsigned short* __restrict__ wTp) {
    __shared__ float tile[32][33];
    const int bid = blockIdx.x, tid = threadIdx.x;
    if (bid < 2048) {
        const int n = 8192 * 768;
        int i = (bid * 256 + tid) * 4;
        const int stride = 2048 * 256 * 4;
        for (; i < n; i += stride) {
            float4 v = *(const float4*)(x + i);
            ushort4 o;
            o.x = f2bf(v.x); o.y = f2bf(v.y); o.z = f2bf(v.z); o.w = f2bf(v.w);
            *(ushort4*)(xb + i) = o;
        }
    } else {
        const float* w; unsigned short* wt; int K, N, bx, by;
        if (bid < 3776) {
            int id = bid - 2048; w = w_attn; wt = wTa; K = 768; N = 2304;
            bx = id % 72; by = id / 72;
        } else {
            int id = bid - 3776; w = w_proj; wt = wTp; K = 768; N = 768;
            bx = id % 24; by = id / 24;
        }
        const int tx = tid & 31, ty = tid >> 5;
        const int n0 = bx * 32, k0 = by * 32;
#pragma unroll
        for (int r = 0; r < 4; r++)
            tile[ty * 4 + r][tx] = w[(size_t)(k0 + ty * 4 + r) * N + n0 + tx];
        __syncthreads();
#pragma unroll
        for (int r = 0; r < 4; r++)
            wt[(size_t)(n0 + ty * 4 + r) * K + k0 + tx] = f2bf(tile[tx][ty * 4 + r]);
    }
}

// ---- GEMM: C[M,N] = A[M,K] * Bt[N,K]^T + bias (unchanged) ----
template <bool OUT_BF16>
__global__ __launch_bounds__(256, 2)
void gemm_bt(const unsigned short* __restrict__ A, const unsigned short* __restrict__ Bt,
             const float* __restrict__ bias, void* __restrict__ Cout,
             unsigned short* __restrict__ Vt,
             int M, int N, int K, int ldc, int qcols, float qscale) {
    __shared__ char smem[65536];
    const int tid = threadIdx.x, wid = tid >> 6, lane = tid & 63;
    const int g = lane >> 4, lr = lane & 15;
    const int m0 = blockIdx.y * 128, n0 = blockIdx.x * 128;
    const int wm = wid >> 1, wn = wid & 1;

    f32x4 acc[4][4];
#pragma unroll
    for (int i = 0; i < 4; i++)
#pragma unroll
        for (int j = 0; j < 4; j++) acc[i][j] = f32x4{0.f, 0.f, 0.f, 0.f};

    const int rbase = lane >> 3;
    const int cSw = ((lane & 7) << 4) ^ (rbase << 4);

    auto STAGE = [&](int buf, int kt) {
        char* base = smem + buf * 32768;
#pragma unroll
        for (int ww = 0; ww < 4; ww++) {
            int w = wid * 4 + ww;
            int r = w * 8 + rbase;
            const unsigned short* srcA = A + (size_t)(m0 + r) * K + kt + (cSw >> 1);
            __builtin_amdgcn_global_load_lds(AS_G(srcA), AS_L(base + w * 1024), 16, 0, 0);
            const unsigned short* srcB = Bt + (size_t)(n0 + r) * K + kt + (cSw >> 1);
            __builtin_amdgcn_global_load_lds(AS_G(srcB), AS_L(base + 16384 + w * 1024), 16, 0, 0);
        }
    };

    const int nk = K >> 6;
    STAGE(0, 0);

    for (int t = 0; t < nk; t++) {
        if (t + 1 < nk) {
            STAGE((t + 1) & 1, (t + 1) << 6);
            asm volatile("s_waitcnt vmcnt(8)" ::: "memory");
        } else {
            asm volatile("s_waitcnt vmcnt(0)" ::: "memory");
        }
        __builtin_amdgcn_s_barrier();
        char* cbase = smem + (t & 1) * 32768;
#pragma unroll
        for (int ks = 0; ks < 2; ks++) {
            s16x8 af[4], bfr[4];
#pragma unroll
            for (int i = 0; i < 4; i++)
                af[i] = *(const s16x8*)(cbase + swz128(wm * 64 + i * 16 + lr, ks * 64 + g * 16));
#pragma unroll
            for (int j = 0; j < 4; j++)
                bfr[j] = *(const s16x8*)(cbase + 16384 + swz128(wn * 64 + j * 16 + lr, ks * 64 + g * 16));
#pragma unroll
            for (int i = 0; i < 4; i++)
#pragma unroll
                for (int j = 0; j < 4; j++)
                    acc[i][j] = MFMA16x16x32(af[i], bfr[j], acc[i][j]);
        }
        BARRIER_LGKM();
    }

#pragma unroll
    for (int j = 0; j < 4; j++) {
        int c = n0 + wn * 64 + j * 16 + lr;
        float bv = bias[c];
        float cscale = (c < qcols) ? qscale : 1.0f;
        if (Vt != nullptr && c >= 1536) {
            int h = (c - 1536) >> 6, d = (c - 1536) & 63;
#pragma unroll
            for (int i = 0; i < 4; i++) {
                int r0 = m0 + wm * 64 + i * 16 + g * 4;
                int bb = r0 >> 11, t0 = r0 & 2047;
                ushort4 o4;
                o4.x = f2bf(acc[i][j][0] + bv);
                o4.y = f2bf(acc[i][j][1] + bv);
                o4.z = f2bf(acc[i][j][2] + bv);
                o4.w = f2bf(acc[i][j][3] + bv);
                *(ushort4*)(Vt + ((((size_t)bb * 12 + h) * 64 + d) << 11) + t0) = o4;
            }
        } else {
#pragma unroll
            for (int i = 0; i < 4; i++) {
#pragma unroll
                for (int rg = 0; rg < 4; rg++) {
                    int r = m0 + wm * 64 + i * 16 + g * 4 + rg;
                    float val = (acc[i][j][rg] + bv) * cscale;
                    if constexpr (OUT_BF16)
                        ((unsigned short*)Cout)[(size_t)r * ldc + c] = f2bf(val);
                    else
                        ((float*)Cout)[(size_t)r * ldc + c] = val;
                }
            }
        }
    }
}

// ---- causal flash attention: swapped QK^T, merged pair, dbuf K/V,
// ones-MFMA row-sum, dual P buffers, software-pipelined A/B phases ----
// Grid 768: s -> xcd=s&7, i=s>>3, grp=xcd*6+(i>>4), qpi=i&15 (XCD-clustered).
// Pair (qtA=qpi, qtB=31-qpi), ONE sweep over tiles 0..qtB.
// LDS 48KB: Kbuf[2] 2x8K | Vbuf[2] 2x8K @+16K | P_B 8K @+32K | P_A 8K @+40K.
// l computed by mfma(P, ones) -> lands in same (g,rg) slot as o: no shuffles.
__global__ __launch_bounds__(256, 2)
void attn_kernel(const unsigned short* __restrict__ qk, const unsigned short* __restrict__ Vt,
                 unsigned short* __restrict__ y) {
    __shared__ char smem[49152];
    const int tid = threadIdx.x, wid = tid >> 6, lane = tid & 63;
    const int g = lane >> 4, lr = lane & 15;
    const int T = 2048;

    const int s = blockIdx.x;
    const int xcd = s & 7, i = s >> 3;
    const int grp = xcd * 6 + (i >> 4);
    const int qpi = i & 15;
    const int h = grp % 12, b = grp / 12;
    const int qtA = qpi, qtB = 31 - qpi;
    const int q0A = qtA * 64, q0B = qtB * 64;

    const int krow = tid >> 2;
    const int kcol = (tid & 3) * 32;

    s16x8 vone;
#pragma unroll
    for (int e = 0; e < 8; e++) vone[e] = (short)0x3F80;   // bf16 1.0

    const unsigned short* qrowA = qk + (size_t)(b * T + q0A + wid * 16 + lr) * 1536 + h * 64;
    const unsigned short* qrowB = qk + (size_t)(b * T + q0B + wid * 16 + lr) * 1536 + h * 64;
    s16x8 aqA[2], aqB[2];
    aqA[0] = *(const s16x8*)(qrowA + g * 8);
    aqA[1] = *(const s16x8*)(qrowA + 32 + g * 8);
    aqB[0] = *(const s16x8*)(qrowB + g * 8);
    aqB[1] = *(const s16x8*)(qrowB + 32 + g * 8);

    f32x4 oA[4], oB[4], lsumA, lsumB;
#pragma unroll
    for (int r = 0; r < 4; r++) { oA[r] = f32x4{0.f, 0.f, 0.f, 0.f}; oB[r] = f32x4{0.f, 0.f, 0.f, 0.f}; }
    lsumA = f32x4{0.f, 0.f, 0.f, 0.f};
    lsumB = f32x4{0.f, 0.f, 0.f, 0.f};

    const unsigned short* pkBase = qk + (size_t)(b * T + krow) * 1536 + 768 + h * 64 + (kcol >> 1);
    const unsigned short* pvBase = Vt + ((((size_t)b * 12 + h) * 64 + krow) << 11) + (kcol >> 1);

    const int ntA = qtA + 1, ntB = qtB + 1;

    // prologue: load tile 0 -> buf0; issue loads for tile 1
    s16x8 k0 = *(const s16x8*)(pkBase);
    s16x8 k1 = *(const s16x8*)(pkBase + 8);
    s16x8 v0 = *(const s16x8*)(pvBase);
    s16x8 v1 = *(const s16x8*)(pvBase + 8);
    *(s16x8*)(smem + swz128(krow, kcol)) = k0;
    *(s16x8*)(smem + swz128(krow, kcol + 16)) = k1;
    *(s16x8*)(smem + 16384 + swz128(krow, kcol)) = v0;
    *(s16x8*)(smem + 16384 + swz128(krow, kcol + 16)) = v1;
    if (ntB > 1) {
        const unsigned short* pk = pkBase + (size_t)64 * 1536;
        k0 = *(const s16x8*)(pk);
        k1 = *(const s16x8*)(pk + 8);
        const unsigned short* pv = pvBase + 64;
        v0 = *(const s16x8*)(pv);
        v1 = *(const s16x8*)(pv + 8);
    }
    BARRIER_LGKM();

    char* const pbaseB = smem + 32768 + wid * 2048;
    char* const pbaseA = smem + 40960 + wid * 2048;
    const int q_rel = wid * 16 + lr;

    for (int t = 0; t < ntB; t++) {
        char* kbase = smem + (t & 1) * 8192;
        char* vbase = smem + 16384 + (t & 1) * 8192;
        const bool actA = (t < ntA);

        // ---- phase 1: QK^T + exp + P-write for B, then A (separate buffers) ----
        {
            f32x4 st[4];
            __builtin_amdgcn_s_setprio(1);
#pragma unroll
            for (int nf = 0; nf < 4; nf++) {
                f32x4 sf = f32x4{0.f, 0.f, 0.f, 0.f};
#pragma unroll
                for (int ks = 0; ks < 2; ks++) {
                    s16x8 ak = *(const s16x8*)(kbase + swz128(nf * 16 + lr, (ks * 32 + g * 8) * 2));
                    sf = MFMA16x16x32(ak, aqB[ks], sf);
                }
                st[nf] = sf;
            }
            __builtin_amdgcn_s_setprio(0);
            const bool diag = (t == ntB - 1);
#pragma unroll
            for (int nf = 0; nf < 4; nf++)
#pragma unroll
                for (int rg = 0; rg < 4; rg++) {
                    float p = __builtin_amdgcn_exp2f(st[nf][rg]);
                    if (diag && (nf * 16 + g * 4 + rg > q_rel)) p = 0.f;
                    st[nf][rg] = p;
                }
#pragma unroll
            for (int nf = 0; nf < 4; nf++) {
                uint2 dw;
                dw.x = cvt_pk_bf2(st[nf][0], st[nf][1]);
                dw.y = cvt_pk_bf2(st[nf][2], st[nf][3]);
                *(uint2*)(pbaseB + swz128(lr, nf * 32 + g * 8)) = dw;
            }
        }
        if (actA) {
            f32x4 st[4];
            __builtin_amdgcn_s_setprio(1);
#pragma unroll
            for (int nf = 0; nf < 4; nf++) {
                f32x4 sf = f32x4{0.f, 0.f, 0.f, 0.f};
#pragma unroll
                for (int ks = 0; ks < 2; ks++) {
                    s16x8 ak = *(const s16x8*)(kbase + swz128(nf * 16 + lr, (ks * 32 + g * 8) * 2));
                    sf = MFMA16x16x32(ak, aqA[ks], sf);
                }
                st[nf] = sf;
            }
            __builtin_amdgcn_s_setprio(0);
            const bool diag = (t == ntA - 1);
#pragma unroll
            for (int nf = 0; nf < 4; nf++)
#pragma unroll
                for (int rg = 0; rg < 4; rg++) {
                    float p = __builtin_amdgcn_exp2f(st[nf][rg]);
                    if (diag && (nf * 16 + g * 4 + rg > q_rel)) p = 0.f;
                    st[nf][rg] = p;
                }
#pragma unroll
            for (int nf = 0; nf < 4; nf++) {
                uint2 dw;
                dw.x = cvt_pk_bf2(st[nf][0], st[nf][1]);
                dw.y = cvt_pk_bf2(st[nf][2], st[nf][3]);
                *(uint2*)(pbaseA + swz128(lr, nf * 32 + g * 8)) = dw;
            }
        }

        // ---- phase 2: P-read + PV + ones-MFMA row-sum for B, then A ----
        {
            s16x8 pf[2];
#pragma unroll
            for (int ks = 0; ks < 2; ks++)
                pf[ks] = *(const s16x8*)(pbaseB + swz128(lr, ks * 64 + g * 16));
            __builtin_amdgcn_s_setprio(1);
#pragma unroll
            for (int nf = 0; nf < 4; nf++) {
#pragma unroll
                for (int ks = 0; ks < 2; ks++) {
                    s16x8 bv = *(const s16x8*)(vbase + swz128(nf * 16 + lr, ks * 64 + g * 16));
                    oB[nf] = MFMA16x16x32(pf[ks], bv, oB[nf]);
                }
            }
            lsumB = MFMA16x16x32(pf[0], vone, lsumB);
            lsumB = MFMA16x16x32(pf[1], vone, lsumB);
            __builtin_amdgcn_s_setprio(0);
        }
        if (actA) {
            s16x8 pf[2];
#pragma unroll
            for (int ks = 0; ks < 2; ks++)
                pf[ks] = *(const s16x8*)(pbaseA + swz128(lr, ks * 64 + g * 16));
            __builtin_amdgcn_s_setprio(1);
#pragma unroll
            for (int nf = 0; nf < 4; nf++) {
#pragma unroll
                for (int ks = 0; ks < 2; ks++) {
                    s16x8 bv = *(const s16x8*)(vbase + swz128(nf * 16 + lr, ks * 64 + g * 16));
                    oA[nf] = MFMA16x16x32(pf[ks], bv, oA[nf]);
                }
            }
            lsumA = MFMA16x16x32(pf[0], vone, lsumA);
            lsumA = MFMA16x16x32(pf[1], vone, lsumA);
            __builtin_amdgcn_s_setprio(0);
        }

        // stage tile t+1 into the other buffer; issue loads for t+2
        if (t + 1 < ntB) {
            char* kn = smem + ((t + 1) & 1) * 8192;
            char* vn = smem + 16384 + ((t + 1) & 1) * 8192;
            *(s16x8*)(kn + swz128(krow, kcol)) = k0;
            *(s16x8*)(kn + swz128(krow, kcol + 16)) = k1;
            *(s16x8*)(vn + swz128(krow, kcol)) = v0;
            *(s16x8*)(vn + swz128(krow, kcol + 16)) = v1;
            if (t + 2 < ntB) {
                const unsigned short* pk = pkBase + (size_t)(t + 2) * 64 * 1536;
                k0 = *(const s16x8*)(pk);
                k1 = *(const s16x8*)(pk + 8);
                const unsigned short* pv = pvBase + (t + 2) * 64;
                v0 = *(const s16x8*)(pv);
                v1 = *(const s16x8*)(pv + 8);
            }
        }
        BARRIER_LGKM();              // single barrier per tile
    }

    // epilogue: lsum[rg] is the row-sum for q = wid*16+g*4+rg — same slot as o
#pragma unroll
    for (int which = 0; which < 2; which++) {
        const f32x4 lsum = which ? lsumB : lsumA;
        const int q0 = which ? q0B : q0A;
        f32x4* o = which ? oB : oA;
        float linv_q[4];
#pragma unroll
        for (int rg = 0; rg < 4; rg++) linv_q[rg] = 1.0f / lsum[rg];
#pragma unroll
        for (int nf = 0; nf < 4; nf++) {
#pragma unroll
            for (int rg = 0; rg < 4; rg++) {
                int row = b * T + q0 + wid * 16 + g * 4 + rg;
                int col = h * 64 + nf * 16 + lr;
                y[(size_t)row * 768 + col] = f2bf(o[nf][rg] * linv_q[rg]);
            }
        }
    }
}

extern "C" void kernel_launch(void* const* d_in, const int* in_sizes, int n_in,
                              void* d_out, int out_size, void* d_ws, size_t ws_size,
                              hipStream_t stream) {
    const float* x      = (const float*)d_in[0];
    const float* w_attn = (const float*)d_in[1];
    const float* b_attn = (const float*)d_in[2];
    const float* w_proj = (const float*)d_in[3];
    const float* b_proj = (const float*)d_in[4];

    char* ws = (char*)d_ws;
    unsigned short* qk  = (unsigned short*)(ws);
    unsigned short* Vt  = (unsigned short*)(ws + 25165824);
    unsigned short* wTa = (unsigned short*)(ws + 37748736);
    unsigned short* wTp = (unsigned short*)(ws + 41287680);

    const bool big = ws_size >= (size_t)55050240;
    unsigned short* xb = (unsigned short*)d_out;
    unsigned short* yb = big ? (unsigned short*)(ws + 42467328)
                             : (unsigned short*)((char*)d_out + 12582912);
    float* projOut = big ? (float*)d_out : (float*)ws;

    prologue_kernel<<<4352, 256, 0, stream>>>(x, xb, w_attn, wTa, w_proj, wTp);

    // qscale = 0.125 * log2(e): softmax scale and exp->exp2 folded into Q
    gemm_bt<true><<<dim3(18, 64), 256, 0, stream>>>(xb, wTa, b_attn, (void*)qk, Vt,
                                                    8192, 2304, 768, 1536, 768, 0.1803368801111244f);
    attn_kernel<<<768, 256, 0, stream>>>(qk, Vt, yb);
    gemm_bt<false><<<dim3(6, 64), 256, 0, stream>>>(yb, wTp, b_proj, (void*)projOut, nullptr,
                                                    8192, 768, 768, 768, 0, 1.0f);
    if (!big)
        hipMemcpyAsync(d_out, projOut, 25165824, hipMemcpyDeviceToDevice, stream);
}